// Round 1
// baseline (560.396 us; speedup 1.0000x reference)
//
#include <hip/hip_runtime.h>
#include <stdint.h>

#define N_NODES 1024
#define NCLS 10
#define KDIM 131072  // 1024*128

typedef unsigned short u16;
typedef __bf16 bf16x8 __attribute__((ext_vector_type(8)));
typedef float f32x4 __attribute__((ext_vector_type(4)));

__device__ __forceinline__ float b2f(u16 u) {
  union { float f; uint32_t u; } v; v.u = ((uint32_t)u) << 16; return v.f;
}
__device__ __forceinline__ u16 f2b(float f) {
  union { float f; uint32_t u; } v; v.f = f;
  uint32_t r = v.u + 0x7FFF + ((v.u >> 16) & 1);
  return (u16)(r >> 16);
}

__device__ __forceinline__ void async_copy16(const u16* g, u16* l) {
  __builtin_amdgcn_global_load_lds(
      (const __attribute__((address_space(1))) void*)g,
      (__attribute__((address_space(3))) void*)l, 16, 0, 0);
}

// ---------------- prep kernels ----------------
__global__ __launch_bounds__(256) void cvt_w_kernel(const float* __restrict__ w,
                                                    u16* __restrict__ o, int n) {
  int i = blockIdx.x * 256 + threadIdx.x;
  if (i < n) o[i] = f2b(w[i]);
}

__global__ __launch_bounds__(256) void prep_wc_kernel(const float* __restrict__ wc,
                                                      u16* __restrict__ o) {
  // o is [16][KDIM]; rows 10..15 zero-padded
  int i = blockIdx.x * 256 + threadIdx.x;  // 16*KDIM total
  int row = i >> 17;
  int col = i & (KDIM - 1);
  o[i] = (row < NCLS) ? f2b(wc[row * KDIM + col]) : (u16)0;
}

__global__ __launch_bounds__(256) void prep_r_kernel(const float* __restrict__ adj,
                                                     float* __restrict__ r) {
  int m = blockIdx.x * 256 + threadIdx.x;
  if (m >= N_NODES) return;
  int i = m >> 5, j = m & 31;
  const float* arow = adj + (size_t)m * N_NODES;
  float s = arow[m];
  if (i > 0)  s += arow[m - 32];
  if (i < 31) s += arow[m + 32];
  if (j > 0)  s += arow[m - 1];
  if (j < 31) s += arow[m + 1];
  r[m] = s;
}

__global__ __launch_bounds__(256) void outinit_kernel(const float* __restrict__ bc,
                                                      float* __restrict__ out) {
  int idx = blockIdx.x * 256 + threadIdx.x;
  if (idx < 256 * NCLS) out[idx] = bc[idx % NCLS];
}

// ---------------- layer 1: h1 = relu((A h0) W1^T + r*b1) ----------------
// block per (b,m); 256 threads = hid channels
__global__ __launch_bounds__(256) void layer1_kernel(
    const float* __restrict__ x,    // [chunk,3,1024]
    const float* __restrict__ adj,
    const float* __restrict__ W1,   // [256,3]
    const float* __restrict__ b1,   // [256]
    const float* __restrict__ r,    // [1024]
    u16* __restrict__ h1)           // [chunk*1024, 256]
{
  int p = blockIdx.x;           // b*1024+m (within chunk)
  int b = p >> 10, m = p & 1023;
  int h = threadIdx.x;
  int i = m >> 5, j = m & 31;
  __shared__ float xs[5][3];    // coef * x, per neighbor per channel
  if (threadIdx.x < 15) {
    int nb = threadIdx.x / 3, c = threadIdx.x % 3;
    int nbr = m; bool valid = true;
    if (nb == 1) { nbr = m - 32; valid = (i > 0); }
    else if (nb == 2) { nbr = m + 32; valid = (i < 31); }
    else if (nb == 3) { nbr = m - 1; valid = (j > 0); }
    else if (nb == 4) { nbr = m + 1; valid = (j < 31); }
    float v = 0.f;
    if (valid) v = adj[(size_t)m * N_NODES + nbr] * x[(size_t)b * 3072 + c * 1024 + nbr];
    xs[nb][c] = v;
  }
  __syncthreads();
  float g0 = xs[0][0] + xs[1][0] + xs[2][0] + xs[3][0] + xs[4][0];
  float g1 = xs[0][1] + xs[1][1] + xs[2][1] + xs[3][1] + xs[4][1];
  float g2 = xs[0][2] + xs[1][2] + xs[2][2] + xs[3][2] + xs[4][2];
  float z = g0 * W1[h * 3] + g1 * W1[h * 3 + 1] + g2 * W1[h * 3 + 2] + r[m] * b1[h];
  h1[(size_t)p * 256 + h] = f2b(fmaxf(z, 0.f));
}

// ---------------- stencil aggregation: g = A h  (F = 256) ----------------
// 256 threads = 4 waves; each wave handles one (b,m); lane covers 4 features
__global__ __launch_bounds__(256) void agg_kernel(
    const u16* __restrict__ h,     // [chunk*1024, 256]
    const float* __restrict__ adj,
    u16* __restrict__ g)           // [chunk*1024, 256]
{
  int p = blockIdx.x * 4 + (threadIdx.x >> 6);
  int lane = threadIdx.x & 63;
  int b = p >> 10, m = p & 1023;
  int i = m >> 5, j = m & 31;
  const u16* base = h + ((size_t)b << 10) * 256;
  const float* arow = adj + (size_t)m * N_NODES;
  int col = lane * 4;
  float a0 = 0.f, a1 = 0.f, a2 = 0.f, a3 = 0.f;
#define ADDN(NBR, CF) { \
    ushort4 v = *(const ushort4*)(base + (size_t)(NBR) * 256 + col); \
    float cf = (CF); \
    a0 += cf * b2f(v.x); a1 += cf * b2f(v.y); a2 += cf * b2f(v.z); a3 += cf * b2f(v.w); }
  ADDN(m, arow[m]);
  if (i > 0)  ADDN(m - 32, arow[m - 32]);
  if (i < 31) ADDN(m + 32, arow[m + 32]);
  if (j > 0)  ADDN(m - 1, arow[m - 1]);
  if (j < 31) ADDN(m + 1, arow[m + 1]);
#undef ADDN
  ushort4 o;
  o.x = f2b(a0); o.y = f2b(a1); o.z = f2b(a2); o.w = f2b(a3);
  *(ushort4*)(g + (size_t)p * 256 + col) = o;
}

// ---------------- GEMM + bias*r + relu: C = relu(A W^T + r⊙bias) ----------------
// A: [M,256] bf16, W: [N,256] bf16, C: [M,N] bf16.  Tile 128x128, BK=32.
__global__ __launch_bounds__(256) void mm_kernel(
    const u16* __restrict__ A, const u16* __restrict__ W,
    const float* __restrict__ bias, const float* __restrict__ r,
    u16* __restrict__ C, int N)
{
  const int K = 256;
  __shared__ u16 As[128 * 32];
  __shared__ u16 Bs[128 * 32];
  int m0 = blockIdx.x * 128;
  int n0 = blockIdx.y * 128;
  int tid = threadIdx.x;
  int w = tid >> 6, l = tid & 63;
  int wm = w >> 1, wn = w & 1;

  f32x4 acc[4][4] = {};

  int srow = w * 32 + (l >> 2);     // staging row (+16 for second call)
  int skoff = (l & 3) * 8;          // staging k offset (elements)
  int lrow = l & 15, lq = l >> 4;

  for (int k0 = 0; k0 < K; k0 += 32) {
    const u16* ga = A + (size_t)(m0 + srow) * K + k0 + skoff;
    const u16* gb = W + (size_t)(n0 + srow) * K + k0 + skoff;
    async_copy16(ga,            &As[(w * 32) * 32]);
    async_copy16(ga + 16 * K,   &As[(w * 32 + 16) * 32]);
    async_copy16(gb,            &Bs[(w * 32) * 32]);
    async_copy16(gb + 16 * K,   &Bs[(w * 32 + 16) * 32]);
    __syncthreads();

    const u16* pa = &As[(wm * 64 + lrow) * 32 + lq * 8];
    const u16* pb = &Bs[(wn * 64 + lrow) * 32 + lq * 8];
    bf16x8 af[4], bf[4];
#pragma unroll
    for (int t = 0; t < 4; t++) {
      af[t] = *(const bf16x8*)(pa + t * 16 * 32);
      bf[t] = *(const bf16x8*)(pb + t * 16 * 32);
    }
#pragma unroll
    for (int mt = 0; mt < 4; mt++)
#pragma unroll
      for (int nt = 0; nt < 4; nt++)
        acc[mt][nt] = __builtin_amdgcn_mfma_f32_16x16x32_bf16(af[mt], bf[nt], acc[mt][nt], 0, 0, 0);
    __syncthreads();
  }

  // epilogue: bias*r, relu, bf16 store
#pragma unroll
  for (int mt = 0; mt < 4; mt++)
#pragma unroll
    for (int nt = 0; nt < 4; nt++) {
      f32x4 v = acc[mt][nt];
      int col = n0 + wn * 64 + nt * 16 + lrow;
      float bs = bias[col];
#pragma unroll
      for (int i2 = 0; i2 < 4; i2++) {
        int row = m0 + wm * 64 + mt * 16 + lq * 4 + i2;
        float val = v[i2] + r[row & 1023] * bs;
        C[(size_t)row * N + col] = f2b(fmaxf(val, 0.f));
      }
    }
}

// ---------------- classifier: out[b,k] += h3[b,:] . Wc[k,:] ----------------
// grid: (chunk/16 m-tiles, 32 k-splits); 4 waves each take 1024-wide K span
__global__ __launch_bounds__(256) void cls_kernel(
    const u16* __restrict__ h3,   // [chunk, KDIM] bf16
    const u16* __restrict__ Wcb,  // [16, KDIM] bf16 (rows 10..15 zero)
    float* __restrict__ out,      // [256, 10]
    int b0)
{
  int mt = blockIdx.x;
  int split = blockIdx.y;
  int w = threadIdx.x >> 6, l = threadIdx.x & 63;
  int lrow = l & 15, lq = l >> 4;
  f32x4 acc = {};
  int kbase = split * 4096 + w * 1024;
  const u16* pa = h3 + (size_t)(mt * 16 + lrow) * KDIM + kbase + lq * 8;
  const u16* pb = Wcb + (size_t)lrow * KDIM + kbase + lq * 8;
#pragma unroll 4
  for (int kk = 0; kk < 1024; kk += 32) {
    bf16x8 a = *(const bf16x8*)(pa + kk);
    bf16x8 b = *(const bf16x8*)(pb + kk);
    acc = __builtin_amdgcn_mfma_f32_16x16x32_bf16(a, b, acc, 0, 0, 0);
  }
  if (lrow < NCLS) {
#pragma unroll
    for (int i2 = 0; i2 < 4; i2++) {
      int b = b0 + mt * 16 + lq * 4 + i2;
      atomicAdd(&out[b * NCLS + lrow], acc[i2]);
    }
  }
}

extern "C" void kernel_launch(void* const* d_in, const int* in_sizes, int n_in,
                              void* d_out, int out_size, void* d_ws, size_t ws_size,
                              hipStream_t stream) {
  const float* x   = (const float*)d_in[0];
  const float* W1  = (const float*)d_in[1];
  const float* b1  = (const float*)d_in[2];
  const float* W2  = (const float*)d_in[3];
  const float* b2  = (const float*)d_in[4];
  const float* W3  = (const float*)d_in[5];
  const float* b3  = (const float*)d_in[6];
  const float* Wc  = (const float*)d_in[7];
  const float* bc  = (const float*)d_in[8];
  const float* adj = (const float*)d_in[9];
  float* out = (float*)d_out;
  const int B = 256;

  // workspace carve-up
  uint8_t* ws = (uint8_t*)d_ws;
  u16* W2b = (u16*)ws;  ws += (size_t)256 * 256 * 2;
  u16* W3b = (u16*)ws;  ws += (size_t)128 * 256 * 2;
  u16* Wcb = (u16*)ws;  ws += (size_t)16 * KDIM * 2;
  float* rr = (float*)ws; ws += 1024 * 4;
  uintptr_t al = ((uintptr_t)ws + 255) & ~(uintptr_t)255;
  ws = (uint8_t*)al;
  size_t used = (size_t)(ws - (uint8_t*)d_ws);
  size_t avail = (ws_size > used) ? ws_size - used : 0;
  int chunk = 256;
  while (chunk > 32 && (size_t)chunk * 1024 * 256 * 2 * 2 > avail) chunk >>= 1;
  u16* bufA = (u16*)ws;
  u16* bufB = bufA + (size_t)chunk * 1024 * 256;

  cvt_w_kernel<<<256, 256, 0, stream>>>(W2, W2b, 256 * 256);
  cvt_w_kernel<<<128, 256, 0, stream>>>(W3, W3b, 128 * 256);
  prep_wc_kernel<<<(16 * KDIM) / 256, 256, 0, stream>>>(Wc, Wcb);
  prep_r_kernel<<<4, 256, 0, stream>>>(adj, rr);
  outinit_kernel<<<(256 * NCLS + 255) / 256, 256, 0, stream>>>(bc, out);

  for (int b0 = 0; b0 < B; b0 += chunk) {
    const float* xb = x + (size_t)b0 * 3 * 1024;
    int M = chunk * 1024;
    layer1_kernel<<<M, 256, 0, stream>>>(xb, adj, W1, b1, rr, bufA);
    agg_kernel<<<M / 4, 256, 0, stream>>>(bufA, adj, bufB);
    {
      dim3 g(M / 128, 2);
      mm_kernel<<<g, 256, 0, stream>>>(bufB, W2b, b2, rr, bufA, 256);
    }
    agg_kernel<<<M / 4, 256, 0, stream>>>(bufA, adj, bufB);
    {
      dim3 g(M / 128, 1);
      mm_kernel<<<g, 256, 0, stream>>>(bufB, W3b, b3, rr, bufA, 128);
    }
    dim3 gc(chunk / 16, 32);
    cls_kernel<<<gc, 256, 0, stream>>>(bufA, Wcb, out, b0);
  }
}

// Round 2
// 399.643 us; speedup vs baseline: 1.4022x; 1.4022x over previous
//
#include <hip/hip_runtime.h>
#include <stdint.h>

#define N_NODES 1024
#define NCLS 10
#define KDIM 131072  // 1024*128

typedef unsigned short u16;
typedef __bf16 bf16x8 __attribute__((ext_vector_type(8)));
typedef float f32x4 __attribute__((ext_vector_type(4)));

__device__ __forceinline__ float b2f(u16 u) {
  union { float f; uint32_t u; } v; v.u = ((uint32_t)u) << 16; return v.f;
}
__device__ __forceinline__ float b2f_lo(uint32_t u) {
  union { float f; uint32_t u; } v; v.u = u << 16; return v.f;
}
__device__ __forceinline__ float b2f_hi(uint32_t u) {
  union { float f; uint32_t u; } v; v.u = u & 0xFFFF0000u; return v.f;
}
__device__ __forceinline__ u16 f2b(float f) {
  union { float f; uint32_t u; } v; v.f = f;
  uint32_t r = v.u + 0x7FFF + ((v.u >> 16) & 1);
  return (u16)(r >> 16);
}
__device__ __forceinline__ uint32_t pack2(float a, float b) {
  return (uint32_t)f2b(a) | ((uint32_t)f2b(b) << 16);
}

__device__ __forceinline__ void async_copy16(const u16* g, u16* l) {
  __builtin_amdgcn_global_load_lds(
      (const __attribute__((address_space(1))) void*)g,
      (__attribute__((address_space(3))) void*)l, 16, 0, 0);
}

// ---------------- prep kernels ----------------
__global__ __launch_bounds__(256) void cvt_w_kernel(const float* __restrict__ w,
                                                    u16* __restrict__ o, int n) {
  int i = blockIdx.x * 256 + threadIdx.x;
  if (i < n) o[i] = f2b(w[i]);
}

__global__ __launch_bounds__(256) void prep_wc_kernel(const float* __restrict__ wc,
                                                      u16* __restrict__ o) {
  int i = blockIdx.x * 256 + threadIdx.x;  // 16*KDIM total
  int row = i >> 17;
  int col = i & (KDIM - 1);
  o[i] = (row < NCLS) ? f2b(wc[row * KDIM + col]) : (u16)0;
}

// stencil tables: nbi[m][5] neighbor index (fallback m), nbc[m][5] coef (0 if invalid), r[m]=row sum
__global__ __launch_bounds__(256) void prep_tab_kernel(const float* __restrict__ adj,
                                                       int* __restrict__ nbi,
                                                       float* __restrict__ nbc,
                                                       float* __restrict__ r) {
  int m = blockIdx.x * 256 + threadIdx.x;
  if (m >= N_NODES) return;
  int i = m >> 5, j = m & 31;
  const float* arow = adj + (size_t)m * N_NODES;
  int n[5]; float c[5];
  n[0] = m;                      c[0] = arow[m];
  n[1] = (i > 0)  ? m - 32 : m;  c[1] = (i > 0)  ? arow[m - 32] : 0.f;
  n[2] = (i < 31) ? m + 32 : m;  c[2] = (i < 31) ? arow[m + 32] : 0.f;
  n[3] = (j > 0)  ? m - 1  : m;  c[3] = (j > 0)  ? arow[m - 1]  : 0.f;
  n[4] = (j < 31) ? m + 1  : m;  c[4] = (j < 31) ? arow[m + 1]  : 0.f;
  float s = 0.f;
#pragma unroll
  for (int t = 0; t < 5; t++) { nbi[m * 5 + t] = n[t]; nbc[m * 5 + t] = c[t]; s += c[t]; }
  r[m] = s;
}

__global__ __launch_bounds__(256) void outinit_kernel(const float* __restrict__ bc,
                                                      float* __restrict__ out) {
  int idx = blockIdx.x * 256 + threadIdx.x;
  if (idx < 256 * NCLS) out[idx] = bc[idx % NCLS];
}

// ---------------- fused layer1 + agg: g2 = A * relu((A x)W1^T + r.b1) ----------------
// block = 64 center nodes (one b), halo 128 ext nodes of h1 in LDS (bf16)
__global__ __launch_bounds__(256) void l1agg_kernel(
    const float* __restrict__ x,    // [chunk,3,1024]
    const float* __restrict__ W1,   // [256,3]
    const float* __restrict__ b1,   // [256]
    const int* __restrict__ nbi, const float* __restrict__ nbc,
    const float* __restrict__ r,    // [1024]
    u16* __restrict__ g)            // [chunk*1024, 256] = A.h1
{
  __shared__ u16 h1s[128 * 256];    // 64 KB
  __shared__ float gxs[128][4];     // agg'd x (3ch) + r
  __shared__ float W1s[768];
  __shared__ float b1s[256];
  int p0 = blockIdx.x * 64;
  int b = p0 >> 10;
  int m0 = p0 & 1023;
  int e0 = m0 - 32;                 // ext window start (may be <0)
  int tid = threadIdx.x;

  b1s[tid] = b1[tid];
  for (int i = tid; i < 768; i += 256) W1s[i] = W1[i];

  // phase A: aggregated x for ext nodes
  if (tid < 128) {
    int n = e0 + tid;
    float g0 = 0.f, g1 = 0.f, g2 = 0.f, rn = 0.f;
    if (n >= 0 && n < N_NODES) {
      const float* xb = x + (size_t)b * 3072;
#pragma unroll
      for (int t = 0; t < 5; t++) {
        int nb = nbi[n * 5 + t]; float cf = nbc[n * 5 + t];
        g0 += cf * xb[nb];
        g1 += cf * xb[1024 + nb];
        g2 += cf * xb[2048 + nb];
      }
      rn = r[n];
    }
    gxs[tid][0] = g0; gxs[tid][1] = g1; gxs[tid][2] = g2; gxs[tid][3] = rn;
  }
  __syncthreads();

  int ch8 = (tid & 31) * 8;
  float w[8][3], bb[8];
#pragma unroll
  for (int c = 0; c < 8; c++) {
    w[c][0] = W1s[(ch8 + c) * 3];
    w[c][1] = W1s[(ch8 + c) * 3 + 1];
    w[c][2] = W1s[(ch8 + c) * 3 + 2];
    bb[c] = b1s[ch8 + c];
  }

  // phase B: h1 for 128 ext nodes -> LDS (bf16)
#pragma unroll
  for (int it = 0; it < 16; it++) {
    int node = (tid >> 5) + it * 8;
    float g0 = gxs[node][0], g1 = gxs[node][1], g2 = gxs[node][2], rn = gxs[node][3];
    uint32_t pk[4];
#pragma unroll
    for (int c = 0; c < 8; c += 2) {
      float z0 = fmaxf(g0 * w[c][0] + g1 * w[c][1] + g2 * w[c][2] + rn * bb[c], 0.f);
      float z1 = fmaxf(g0 * w[c+1][0] + g1 * w[c+1][1] + g2 * w[c+1][2] + rn * bb[c+1], 0.f);
      pk[c >> 1] = pack2(z0, z1);
    }
    *(uint4*)&h1s[node * 256 + ch8] = *(uint4*)pk;
  }
  __syncthreads();

  // phase C: aggregate center 64 nodes, write g (NO relu)
#pragma unroll
  for (int it = 0; it < 8; it++) {
    int node = (tid >> 5) + it * 8;   // 0..63
    int m = m0 + node;
    float acc[8] = {};
#pragma unroll
    for (int t = 0; t < 5; t++) {
      int nb = nbi[m * 5 + t]; float cf = nbc[m * 5 + t];
      uint4 v = *(const uint4*)&h1s[(nb - e0) * 256 + ch8];
      acc[0] += cf * b2f_lo(v.x); acc[1] += cf * b2f_hi(v.x);
      acc[2] += cf * b2f_lo(v.y); acc[3] += cf * b2f_hi(v.y);
      acc[4] += cf * b2f_lo(v.z); acc[5] += cf * b2f_hi(v.z);
      acc[6] += cf * b2f_lo(v.w); acc[7] += cf * b2f_hi(v.w);
    }
    uint4 o;
    o.x = pack2(acc[0], acc[1]); o.y = pack2(acc[2], acc[3]);
    o.z = pack2(acc[4], acc[5]); o.w = pack2(acc[6], acc[7]);
    *(uint4*)&g[(size_t)(p0 + node) * 256 + ch8] = o;
  }
}

// ---------------- stencil aggregation: g = A h (F=256), half-wave per node ----------------
__global__ __launch_bounds__(256) void agg_kernel(
    const u16* __restrict__ h,     // [chunk*1024, 256]
    const int* __restrict__ nbi, const float* __restrict__ nbc,
    u16* __restrict__ g)
{
  int p = (blockIdx.x * 256 + threadIdx.x) >> 5;   // node id
  int lane = threadIdx.x & 31;
  int b = p >> 10, m = p & 1023;
  const u16* base = h + ((size_t)b << 10) * 256;
  int col = lane * 8;
  float acc[8] = {};
#pragma unroll
  for (int t = 0; t < 5; t++) {
    int nb = nbi[m * 5 + t]; float cf = nbc[m * 5 + t];
    uint4 v = *(const uint4*)(base + (size_t)nb * 256 + col);
    acc[0] += cf * b2f_lo(v.x); acc[1] += cf * b2f_hi(v.x);
    acc[2] += cf * b2f_lo(v.y); acc[3] += cf * b2f_hi(v.y);
    acc[4] += cf * b2f_lo(v.z); acc[5] += cf * b2f_hi(v.z);
    acc[6] += cf * b2f_lo(v.w); acc[7] += cf * b2f_hi(v.w);
  }
  uint4 o;
  o.x = pack2(acc[0], acc[1]); o.y = pack2(acc[2], acc[3]);
  o.z = pack2(acc[4], acc[5]); o.w = pack2(acc[6], acc[7]);
  *(uint4*)(g + (size_t)p * 256 + col) = o;
}

// ---------------- GEMM + bias*r + relu: C = relu(A W^T + r.bias) ----------------
__global__ __launch_bounds__(256) void mm_kernel(
    const u16* __restrict__ A, const u16* __restrict__ W,
    const float* __restrict__ bias, const float* __restrict__ r,
    u16* __restrict__ C, int N)
{
  const int K = 256;
  __shared__ u16 As[128 * 32];
  __shared__ u16 Bs[128 * 32];
  int m0 = blockIdx.x * 128;
  int n0 = blockIdx.y * 128;
  int tid = threadIdx.x;
  int w = tid >> 6, l = tid & 63;
  int wm = w >> 1, wn = w & 1;

  f32x4 acc[4][4] = {};

  int srow = w * 32 + (l >> 2);
  int skoff = (l & 3) * 8;
  int lrow = l & 15, lq = l >> 4;

  for (int k0 = 0; k0 < K; k0 += 32) {
    const u16* ga = A + (size_t)(m0 + srow) * K + k0 + skoff;
    const u16* gb = W + (size_t)(n0 + srow) * K + k0 + skoff;
    async_copy16(ga,          &As[(w * 32) * 32]);
    async_copy16(ga + 16 * K, &As[(w * 32 + 16) * 32]);
    async_copy16(gb,          &Bs[(w * 32) * 32]);
    async_copy16(gb + 16 * K, &Bs[(w * 32 + 16) * 32]);
    __syncthreads();

    const u16* pa = &As[(wm * 64 + lrow) * 32 + lq * 8];
    const u16* pb = &Bs[(wn * 64 + lrow) * 32 + lq * 8];
    bf16x8 af[4], bf[4];
#pragma unroll
    for (int t = 0; t < 4; t++) {
      af[t] = *(const bf16x8*)(pa + t * 16 * 32);
      bf[t] = *(const bf16x8*)(pb + t * 16 * 32);
    }
#pragma unroll
    for (int mt = 0; mt < 4; mt++)
#pragma unroll
      for (int nt = 0; nt < 4; nt++)
        acc[mt][nt] = __builtin_amdgcn_mfma_f32_16x16x32_bf16(af[mt], bf[nt], acc[mt][nt], 0, 0, 0);
    __syncthreads();
  }

#pragma unroll
  for (int mt = 0; mt < 4; mt++)
#pragma unroll
    for (int nt = 0; nt < 4; nt++) {
      f32x4 v = acc[mt][nt];
      int col = n0 + wn * 64 + nt * 16 + lrow;
      float bs = bias[col];
#pragma unroll
      for (int i2 = 0; i2 < 4; i2++) {
        int row = m0 + wm * 64 + mt * 16 + lq * 4 + i2;
        float val = v[i2] + r[row & 1023] * bs;
        C[(size_t)row * N + col] = f2b(fmaxf(val, 0.f));
      }
    }
}

// ---------------- classifier ----------------
__global__ __launch_bounds__(256) void cls_kernel(
    const u16* __restrict__ h3,   // [chunk, KDIM] bf16
    const u16* __restrict__ Wcb,  // [16, KDIM] bf16 (rows 10..15 zero)
    float* __restrict__ out,      // [256, 10]
    int b0)
{
  int mt = blockIdx.x;
  int split = blockIdx.y;
  int w = threadIdx.x >> 6, l = threadIdx.x & 63;
  int lrow = l & 15, lq = l >> 4;
  f32x4 acc = {};
  int kbase = split * 4096 + w * 1024;
  const u16* pa = h3 + (size_t)(mt * 16 + lrow) * KDIM + kbase + lq * 8;
  const u16* pb = Wcb + (size_t)lrow * KDIM + kbase + lq * 8;
#pragma unroll 4
  for (int kk = 0; kk < 1024; kk += 32) {
    bf16x8 a = *(const bf16x8*)(pa + kk);
    bf16x8 b = *(const bf16x8*)(pb + kk);
    acc = __builtin_amdgcn_mfma_f32_16x16x32_bf16(a, b, acc, 0, 0, 0);
  }
  if (lrow < NCLS) {
#pragma unroll
    for (int i2 = 0; i2 < 4; i2++) {
      int b = b0 + mt * 16 + lq * 4 + i2;
      atomicAdd(&out[b * NCLS + lrow], acc[i2]);
    }
  }
}

extern "C" void kernel_launch(void* const* d_in, const int* in_sizes, int n_in,
                              void* d_out, int out_size, void* d_ws, size_t ws_size,
                              hipStream_t stream) {
  const float* x   = (const float*)d_in[0];
  const float* W1  = (const float*)d_in[1];
  const float* b1  = (const float*)d_in[2];
  const float* W2  = (const float*)d_in[3];
  const float* b2  = (const float*)d_in[4];
  const float* W3  = (const float*)d_in[5];
  const float* b3  = (const float*)d_in[6];
  const float* Wc  = (const float*)d_in[7];
  const float* bc  = (const float*)d_in[8];
  const float* adj = (const float*)d_in[9];
  float* out = (float*)d_out;
  const int B = 256;

  uint8_t* ws = (uint8_t*)d_ws;
  u16* W2b = (u16*)ws;  ws += (size_t)256 * 256 * 2;
  u16* W3b = (u16*)ws;  ws += (size_t)128 * 256 * 2;
  u16* Wcb = (u16*)ws;  ws += (size_t)16 * KDIM * 2;
  float* rr  = (float*)ws; ws += 1024 * 4;
  int*   nbi = (int*)ws;   ws += 1024 * 5 * 4;
  float* nbc = (float*)ws; ws += 1024 * 5 * 4;
  uintptr_t al = ((uintptr_t)ws + 255) & ~(uintptr_t)255;
  ws = (uint8_t*)al;
  size_t used = (size_t)(ws - (uint8_t*)d_ws);
  size_t avail = (ws_size > used) ? ws_size - used : 0;
  int chunk = 256;
  while (chunk > 32 && (size_t)chunk * 1024 * 256 * 2 * 2 > avail) chunk >>= 1;
  u16* bufA = (u16*)ws;
  u16* bufB = bufA + (size_t)chunk * 1024 * 256;

  cvt_w_kernel<<<256, 256, 0, stream>>>(W2, W2b, 256 * 256);
  cvt_w_kernel<<<128, 256, 0, stream>>>(W3, W3b, 128 * 256);
  prep_wc_kernel<<<(16 * KDIM) / 256, 256, 0, stream>>>(Wc, Wcb);
  prep_tab_kernel<<<4, 256, 0, stream>>>(adj, nbi, nbc, rr);
  outinit_kernel<<<(256 * NCLS + 255) / 256, 256, 0, stream>>>(bc, out);

  for (int b0 = 0; b0 < B; b0 += chunk) {
    const float* xb = x + (size_t)b0 * 3 * 1024;
    int M = chunk * 1024;
    // g2 = A.h1  -> bufB
    l1agg_kernel<<<M / 64, 256, 0, stream>>>(xb, W1, b1, nbi, nbc, rr, bufB);
    // h2 = relu(g2 W2^T + r.b2) -> bufA
    {
      dim3 g(M / 128, 2);
      mm_kernel<<<g, 256, 0, stream>>>(bufB, W2b, b2, rr, bufA, 256);
    }
    // g3 = A.h2 -> bufB
    agg_kernel<<<M / 8, 256, 0, stream>>>(bufA, nbi, nbc, bufB);
    // h3 = relu(g3 W3^T + r.b3) -> bufA
    {
      dim3 g(M / 128, 1);
      mm_kernel<<<g, 256, 0, stream>>>(bufB, W3b, b3, rr, bufA, 128);
    }
    dim3 gc(chunk / 16, 32);
    cls_kernel<<<gc, 256, 0, stream>>>(bufA, Wcb, out, b0);
  }
}

// Round 3
// 378.796 us; speedup vs baseline: 1.4794x; 1.0550x over previous
//
#include <hip/hip_runtime.h>
#include <stdint.h>

#define N_NODES 1024
#define NCLS 10
#define KDIM 131072  // 1024*128

typedef unsigned short u16;
typedef __bf16 bf16x8 __attribute__((ext_vector_type(8)));
typedef float f32x4 __attribute__((ext_vector_type(4)));

__device__ __forceinline__ float b2f(u16 u) {
  union { float f; uint32_t u; } v; v.u = ((uint32_t)u) << 16; return v.f;
}
__device__ __forceinline__ float b2f_lo(uint32_t u) {
  union { float f; uint32_t u; } v; v.u = u << 16; return v.f;
}
__device__ __forceinline__ float b2f_hi(uint32_t u) {
  union { float f; uint32_t u; } v; v.u = u & 0xFFFF0000u; return v.f;
}
__device__ __forceinline__ u16 f2b(float f) {
  union { float f; uint32_t u; } v; v.f = f;
  uint32_t r = v.u + 0x7FFF + ((v.u >> 16) & 1);
  return (u16)(r >> 16);
}
__device__ __forceinline__ uint32_t pack2(float a, float b) {
  return (uint32_t)f2b(a) | ((uint32_t)f2b(b) << 16);
}

__device__ __forceinline__ void async_copy16(const u16* g, u16* l) {
  __builtin_amdgcn_global_load_lds(
      (const __attribute__((address_space(1))) void*)g,
      (__attribute__((address_space(3))) void*)l, 16, 0, 0);
}

// ---------------- prep kernels ----------------
__global__ __launch_bounds__(256) void cvt_w_kernel(const float* __restrict__ w,
                                                    u16* __restrict__ o, int n) {
  int i = blockIdx.x * 256 + threadIdx.x;
  if (i < n) o[i] = f2b(w[i]);
}

__global__ __launch_bounds__(256) void prep_wc_kernel(const float* __restrict__ wc,
                                                      u16* __restrict__ o) {
  int i = blockIdx.x * 256 + threadIdx.x;  // 16*KDIM total
  int row = i >> 17;
  int col = i & (KDIM - 1);
  o[i] = (row < NCLS) ? f2b(wc[row * KDIM + col]) : (u16)0;
}

// stencil tables: nbi[m][5] neighbor index (fallback m), nbc[m][5] coef (0 if invalid), r[m]=row sum
__global__ __launch_bounds__(256) void prep_tab_kernel(const float* __restrict__ adj,
                                                       int* __restrict__ nbi,
                                                       float* __restrict__ nbc,
                                                       float* __restrict__ r) {
  int m = blockIdx.x * 256 + threadIdx.x;
  if (m >= N_NODES) return;
  int i = m >> 5, j = m & 31;
  const float* arow = adj + (size_t)m * N_NODES;
  int n[5]; float c[5];
  n[0] = m;                      c[0] = arow[m];
  n[1] = (i > 0)  ? m - 32 : m;  c[1] = (i > 0)  ? arow[m - 32] : 0.f;
  n[2] = (i < 31) ? m + 32 : m;  c[2] = (i < 31) ? arow[m + 32] : 0.f;
  n[3] = (j > 0)  ? m - 1  : m;  c[3] = (j > 0)  ? arow[m - 1]  : 0.f;
  n[4] = (j < 31) ? m + 1  : m;  c[4] = (j < 31) ? arow[m + 1]  : 0.f;
  float s = 0.f;
#pragma unroll
  for (int t = 0; t < 5; t++) { nbi[m * 5 + t] = n[t]; nbc[m * 5 + t] = c[t]; s += c[t]; }
  r[m] = s;
}

__global__ __launch_bounds__(256) void outinit_kernel(const float* __restrict__ bc,
                                                      float* __restrict__ out) {
  int idx = blockIdx.x * 256 + threadIdx.x;
  if (idx < 256 * NCLS) out[idx] = bc[idx % NCLS];
}

// ---------------- fused layer1 + agg: g2 = A * relu((A x)W1^T + r.b1) ----------------
__global__ __launch_bounds__(256) void l1agg_kernel(
    const float* __restrict__ x,    // [chunk,3,1024]
    const float* __restrict__ W1,   // [256,3]
    const float* __restrict__ b1,   // [256]
    const int* __restrict__ nbi, const float* __restrict__ nbc,
    const float* __restrict__ r,    // [1024]
    u16* __restrict__ g)            // [chunk*1024, 256] = A.h1
{
  __shared__ u16 h1s[128 * 256];    // 64 KB
  __shared__ float gxs[128][4];
  __shared__ float W1s[768];
  __shared__ float b1s[256];
  int p0 = blockIdx.x * 64;
  int b = p0 >> 10;
  int m0 = p0 & 1023;
  int e0 = m0 - 32;
  int tid = threadIdx.x;

  b1s[tid] = b1[tid];
  for (int i = tid; i < 768; i += 256) W1s[i] = W1[i];

  if (tid < 128) {
    int n = e0 + tid;
    float g0 = 0.f, g1 = 0.f, g2 = 0.f, rn = 0.f;
    if (n >= 0 && n < N_NODES) {
      const float* xb = x + (size_t)b * 3072;
#pragma unroll
      for (int t = 0; t < 5; t++) {
        int nb = nbi[n * 5 + t]; float cf = nbc[n * 5 + t];
        g0 += cf * xb[nb];
        g1 += cf * xb[1024 + nb];
        g2 += cf * xb[2048 + nb];
      }
      rn = r[n];
    }
    gxs[tid][0] = g0; gxs[tid][1] = g1; gxs[tid][2] = g2; gxs[tid][3] = rn;
  }
  __syncthreads();

  int ch8 = (tid & 31) * 8;
  float w[8][3], bb[8];
#pragma unroll
  for (int c = 0; c < 8; c++) {
    w[c][0] = W1s[(ch8 + c) * 3];
    w[c][1] = W1s[(ch8 + c) * 3 + 1];
    w[c][2] = W1s[(ch8 + c) * 3 + 2];
    bb[c] = b1s[ch8 + c];
  }

#pragma unroll
  for (int it = 0; it < 16; it++) {
    int node = (tid >> 5) + it * 8;
    float g0 = gxs[node][0], g1 = gxs[node][1], g2 = gxs[node][2], rn = gxs[node][3];
    uint32_t pk[4];
#pragma unroll
    for (int c = 0; c < 8; c += 2) {
      float z0 = fmaxf(g0 * w[c][0] + g1 * w[c][1] + g2 * w[c][2] + rn * bb[c], 0.f);
      float z1 = fmaxf(g0 * w[c+1][0] + g1 * w[c+1][1] + g2 * w[c+1][2] + rn * bb[c+1], 0.f);
      pk[c >> 1] = pack2(z0, z1);
    }
    *(uint4*)&h1s[node * 256 + ch8] = *(uint4*)pk;
  }
  __syncthreads();

#pragma unroll
  for (int it = 0; it < 8; it++) {
    int node = (tid >> 5) + it * 8;
    int m = m0 + node;
    float acc[8] = {};
#pragma unroll
    for (int t = 0; t < 5; t++) {
      int nb = nbi[m * 5 + t]; float cf = nbc[m * 5 + t];
      uint4 v = *(const uint4*)&h1s[(nb - e0) * 256 + ch8];
      acc[0] += cf * b2f_lo(v.x); acc[1] += cf * b2f_hi(v.x);
      acc[2] += cf * b2f_lo(v.y); acc[3] += cf * b2f_hi(v.y);
      acc[4] += cf * b2f_lo(v.z); acc[5] += cf * b2f_hi(v.z);
      acc[6] += cf * b2f_lo(v.w); acc[7] += cf * b2f_hi(v.w);
    }
    uint4 o;
    o.x = pack2(acc[0], acc[1]); o.y = pack2(acc[2], acc[3]);
    o.z = pack2(acc[4], acc[5]); o.w = pack2(acc[6], acc[7]);
    *(uint4*)&g[(size_t)(p0 + node) * 256 + ch8] = o;
  }
}

// ---------------- GEMM + bias*r + relu: C = relu(A W^T + r.bias) ----------------
// BK=64, XOR-swizzled staging (glds constraint: contiguous lane layout; swizzle breaks
// the 128B-row-stride 16-way bank conflict back to the 8-round minimum).
__global__ __launch_bounds__(256) void mm_kernel(
    const u16* __restrict__ A, const u16* __restrict__ W,
    const float* __restrict__ bias, const float* __restrict__ r,
    u16* __restrict__ C, int N)
{
  const int K = 256;
  __shared__ u16 As[128 * 64];
  __shared__ u16 Bs[128 * 64];
  int m0 = blockIdx.x * 128;
  int n0 = blockIdx.y * 128;
  int tid = threadIdx.x;
  int w = tid >> 6, l = tid & 63;
  int wm = w >> 1, wn = w & 1;

  f32x4 acc[4][4] = {};

  int r8 = l >> 3, oct = l & 7;
  int so = (oct ^ r8) << 3;                 // swizzled element offset in staging
  int lrow = l & 15, lq = l >> 4;
  int o0 = (lq ^ (lrow & 7)) << 3;          // phys octet for k-half 0
  int o1 = o0 ^ 32;                         // k-half 1: (oct|4)^s == (oct^s)^4

  const u16* ga0 = A + (size_t)(m0 + w * 32 + r8) * K + so;
  const u16* gb0 = W + (size_t)(n0 + w * 32 + r8) * K + so;

  for (int k0 = 0; k0 < K; k0 += 64) {
#pragma unroll
    for (int q = 0; q < 4; q++) {
      async_copy16(ga0 + q * 8 * K + k0, &As[(w * 32 + q * 8) * 64]);
      async_copy16(gb0 + q * 8 * K + k0, &Bs[(w * 32 + q * 8) * 64]);
    }
    __syncthreads();

    const u16* pa = &As[(wm * 64 + lrow) * 64];
    const u16* pb = &Bs[(wn * 64 + lrow) * 64];
    bf16x8 af[4][2], bf[4][2];
#pragma unroll
    for (int t = 0; t < 4; t++) {
      af[t][0] = *(const bf16x8*)(pa + t * 16 * 64 + o0);
      af[t][1] = *(const bf16x8*)(pa + t * 16 * 64 + o1);
      bf[t][0] = *(const bf16x8*)(pb + t * 16 * 64 + o0);
      bf[t][1] = *(const bf16x8*)(pb + t * 16 * 64 + o1);
    }
#pragma unroll
    for (int kh = 0; kh < 2; kh++)
#pragma unroll
      for (int mt = 0; mt < 4; mt++)
#pragma unroll
        for (int nt = 0; nt < 4; nt++)
          acc[mt][nt] = __builtin_amdgcn_mfma_f32_16x16x32_bf16(af[mt][kh], bf[nt][kh], acc[mt][nt], 0, 0, 0);
    __syncthreads();
  }

#pragma unroll
  for (int mt = 0; mt < 4; mt++)
#pragma unroll
    for (int nt = 0; nt < 4; nt++) {
      f32x4 v = acc[mt][nt];
      int col = n0 + wn * 64 + nt * 16 + lrow;
      float bs = bias[col];
#pragma unroll
      for (int i2 = 0; i2 < 4; i2++) {
        int row = m0 + wm * 64 + mt * 16 + lq * 4 + i2;
        float val = v[i2] + r[row & 1023] * bs;
        C[(size_t)row * N + col] = f2b(fmaxf(val, 0.f));
      }
    }
}

// ---------------- fused agg + GEMM: h3 = relu((A h2) W3^T + r.b3) ----------------
// A-tile aggregated on the fly from h2 (5-nbr register FMA) into padded LDS.
__global__ __launch_bounds__(256) void mm3agg_kernel(
    const u16* __restrict__ H,      // h2 [chunk*1024, 256]
    const u16* __restrict__ W,      // W3b [128, 256]
    const float* __restrict__ bias, const float* __restrict__ r,
    const int* __restrict__ nbi, const float* __restrict__ nbc,
    u16* __restrict__ C)            // h3 [chunk*1024, 128]
{
  const int K = 256, N = 128;
  const int AST = 72;               // padded A stride (elems)
  __shared__ u16 As[128 * AST];
  __shared__ u16 Bs[128 * 64];
  int m0 = blockIdx.x * 128;
  int tid = threadIdx.x;
  int w = tid >> 6, l = tid & 63;
  int wm = w >> 1, wn = w & 1;

  f32x4 acc[4][4] = {};

  // aggregation assignment: 2 threads per A-row, 32 cols each
  int arow = tid >> 1;
  int acol = (tid & 1) * 32;
  int pg = m0 + arow;
  int node = pg & 1023;
  const u16* hb = H + ((size_t)(pg >> 10) << 10) * 256;
  const u16* nbp[5]; float cf[5];
#pragma unroll
  for (int j = 0; j < 5; j++) {
    nbp[j] = hb + (size_t)nbi[node * 5 + j] * 256 + acol;
    cf[j] = nbc[node * 5 + j];
  }

  // B staging/reads (same swizzle as mm_kernel)
  int r8 = l >> 3, oct = l & 7;
  int so = (oct ^ r8) << 3;
  const u16* gb0 = W + (size_t)(w * 32 + r8) * K + so;
  int lrow = l & 15, lq = l >> 4;
  int o0 = (lq ^ (lrow & 7)) << 3;
  int o1 = o0 ^ 32;

  for (int k0 = 0; k0 < K; k0 += 64) {
#pragma unroll
    for (int q = 0; q < 4; q++)
      async_copy16(gb0 + q * 8 * K + k0, &Bs[(w * 32 + q * 8) * 64]);

    // aggregate this thread's 32 cols of its A-row
#pragma unroll
    for (int half = 0; half < 2; half++) {
      uint4 L[5][2];
#pragma unroll
      for (int j = 0; j < 5; j++) {
        L[j][0] = *(const uint4*)(nbp[j] + k0 + half * 16);
        L[j][1] = *(const uint4*)(nbp[j] + k0 + half * 16 + 8);
      }
      float a0[8] = {}, a1[8] = {};
#pragma unroll
      for (int j = 0; j < 5; j++) {
        float c = cf[j];
        const uint32_t* u0 = (const uint32_t*)&L[j][0];
        const uint32_t* u1 = (const uint32_t*)&L[j][1];
#pragma unroll
        for (int e = 0; e < 4; e++) {
          a0[2*e]   += c * b2f_lo(u0[e]); a0[2*e+1] += c * b2f_hi(u0[e]);
          a1[2*e]   += c * b2f_lo(u1[e]); a1[2*e+1] += c * b2f_hi(u1[e]);
        }
      }
      uint4 oa, ob;
      oa.x = pack2(a0[0], a0[1]); oa.y = pack2(a0[2], a0[3]);
      oa.z = pack2(a0[4], a0[5]); oa.w = pack2(a0[6], a0[7]);
      ob.x = pack2(a1[0], a1[1]); ob.y = pack2(a1[2], a1[3]);
      ob.z = pack2(a1[4], a1[5]); ob.w = pack2(a1[6], a1[7]);
      *(uint4*)&As[arow * AST + acol + half * 16]     = oa;
      *(uint4*)&As[arow * AST + acol + half * 16 + 8] = ob;
    }
    __syncthreads();

    const u16* pa = &As[(wm * 64 + lrow) * AST];
    const u16* pb = &Bs[(wn * 64 + lrow) * 64];
    bf16x8 af[4][2], bf[4][2];
#pragma unroll
    for (int t = 0; t < 4; t++) {
      af[t][0] = *(const bf16x8*)(pa + t * 16 * AST + lq * 8);
      af[t][1] = *(const bf16x8*)(pa + t * 16 * AST + 32 + lq * 8);
      bf[t][0] = *(const bf16x8*)(pb + t * 16 * 64 + o0);
      bf[t][1] = *(const bf16x8*)(pb + t * 16 * 64 + o1);
    }
#pragma unroll
    for (int kh = 0; kh < 2; kh++)
#pragma unroll
      for (int mt = 0; mt < 4; mt++)
#pragma unroll
        for (int nt = 0; nt < 4; nt++)
          acc[mt][nt] = __builtin_amdgcn_mfma_f32_16x16x32_bf16(af[mt][kh], bf[nt][kh], acc[mt][nt], 0, 0, 0);
    __syncthreads();
  }

#pragma unroll
  for (int mt = 0; mt < 4; mt++)
#pragma unroll
    for (int nt = 0; nt < 4; nt++) {
      f32x4 v = acc[mt][nt];
      int col = wn * 64 + nt * 16 + lrow;
      float bs = bias[col];
#pragma unroll
      for (int i2 = 0; i2 < 4; i2++) {
        int row = m0 + wm * 64 + mt * 16 + lq * 4 + i2;
        float val = v[i2] + r[row & 1023] * bs;
        C[(size_t)row * N + col] = f2b(fmaxf(val, 0.f));
      }
    }
}

// ---------------- classifier ----------------
__global__ __launch_bounds__(256) void cls_kernel(
    const u16* __restrict__ h3,   // [chunk, KDIM] bf16
    const u16* __restrict__ Wcb,  // [16, KDIM] bf16 (rows 10..15 zero)
    float* __restrict__ out,      // [256, 10]
    int b0)
{
  int mt = blockIdx.x;
  int split = blockIdx.y;
  int w = threadIdx.x >> 6, l = threadIdx.x & 63;
  int lrow = l & 15, lq = l >> 4;
  f32x4 acc = {};
  int kbase = split * 4096 + w * 1024;
  const u16* pa = h3 + (size_t)(mt * 16 + lrow) * KDIM + kbase + lq * 8;
  const u16* pb = Wcb + (size_t)lrow * KDIM + kbase + lq * 8;
#pragma unroll 4
  for (int kk = 0; kk < 1024; kk += 32) {
    bf16x8 a = *(const bf16x8*)(pa + kk);
    bf16x8 b = *(const bf16x8*)(pb + kk);
    acc = __builtin_amdgcn_mfma_f32_16x16x32_bf16(a, b, acc, 0, 0, 0);
  }
  if (lrow < NCLS) {
#pragma unroll
    for (int i2 = 0; i2 < 4; i2++) {
      int b = b0 + mt * 16 + lq * 4 + i2;
      atomicAdd(&out[b * NCLS + lrow], acc[i2]);
    }
  }
}

extern "C" void kernel_launch(void* const* d_in, const int* in_sizes, int n_in,
                              void* d_out, int out_size, void* d_ws, size_t ws_size,
                              hipStream_t stream) {
  const float* x   = (const float*)d_in[0];
  const float* W1  = (const float*)d_in[1];
  const float* b1  = (const float*)d_in[2];
  const float* W2  = (const float*)d_in[3];
  const float* b2  = (const float*)d_in[4];
  const float* W3  = (const float*)d_in[5];
  const float* b3  = (const float*)d_in[6];
  const float* Wc  = (const float*)d_in[7];
  const float* bc  = (const float*)d_in[8];
  const float* adj = (const float*)d_in[9];
  float* out = (float*)d_out;
  const int B = 256;

  uint8_t* ws = (uint8_t*)d_ws;
  u16* W2b = (u16*)ws;  ws += (size_t)256 * 256 * 2;
  u16* W3b = (u16*)ws;  ws += (size_t)128 * 256 * 2;
  u16* Wcb = (u16*)ws;  ws += (size_t)16 * KDIM * 2;
  float* rr  = (float*)ws; ws += 1024 * 4;
  int*   nbi = (int*)ws;   ws += 1024 * 5 * 4;
  float* nbc = (float*)ws; ws += 1024 * 5 * 4;
  uintptr_t al = ((uintptr_t)ws + 255) & ~(uintptr_t)255;
  ws = (uint8_t*)al;
  size_t used = (size_t)(ws - (uint8_t*)d_ws);
  size_t avail = (ws_size > used) ? ws_size - used : 0;
  int chunk = 256;
  while (chunk > 32 && (size_t)chunk * 1024 * 256 * 2 * 2 > avail) chunk >>= 1;
  u16* bufA = (u16*)ws;
  u16* bufB = bufA + (size_t)chunk * 1024 * 256;

  cvt_w_kernel<<<256, 256, 0, stream>>>(W2, W2b, 256 * 256);
  cvt_w_kernel<<<128, 256, 0, stream>>>(W3, W3b, 128 * 256);
  prep_wc_kernel<<<(16 * KDIM) / 256, 256, 0, stream>>>(Wc, Wcb);
  prep_tab_kernel<<<4, 256, 0, stream>>>(adj, nbi, nbc, rr);
  outinit_kernel<<<(256 * NCLS + 255) / 256, 256, 0, stream>>>(bc, out);

  for (int b0 = 0; b0 < B; b0 += chunk) {
    const float* xb = x + (size_t)b0 * 3 * 1024;
    int M = chunk * 1024;
    // g2 = A.h1  -> bufB
    l1agg_kernel<<<M / 64, 256, 0, stream>>>(xb, W1, b1, nbi, nbc, rr, bufB);
    // h2 = relu(g2 W2^T + r.b2) -> bufA
    {
      dim3 g(M / 128, 2);
      mm_kernel<<<g, 256, 0, stream>>>(bufB, W2b, b2, rr, bufA, 256);
    }
    // h3 = relu((A.h2) W3^T + r.b3) -> bufB   (agg fused into staging)
    mm3agg_kernel<<<M / 128, 256, 0, stream>>>(bufA, W3b, b3, rr, nbi, nbc, bufB);
    dim3 gc(chunk / 16, 32);
    cls_kernel<<<gc, 256, 0, stream>>>(bufB, Wcb, out, b0);
  }
}